// Round 6
// baseline (137.236 us; speedup 1.0000x reference)
//
#include <hip/hip_runtime.h>

#define TEMP 0.07f
#define NROWSLOT 16
#define NSLOT 80   // 16 row-side (chunk m) + 64 col-side (row-tile I)

typedef __attribute__((ext_vector_type(4))) float f32x4;
typedef __attribute__((ext_vector_type(4))) int   i32x4;
typedef __attribute__((ext_vector_type(8))) int   i32x8;

// L2-normalize rows of X (fp32, N x 512) -> fp8 e4m3 (1 B/elem). One wave/row.
// Also zeroes the scalar output (replaces a hipMemsetAsync dispatch).
__global__ __launch_bounds__(256) void knorm(const float* __restrict__ X,
                                             unsigned char* __restrict__ Fq,
                                             float* __restrict__ out, int D) {
  if (blockIdx.x == 0 && threadIdx.x == 0) *out = 0.f;
  int row = blockIdx.x * 4 + (threadIdx.x >> 6);
  int lane = threadIdx.x & 63;
  const float4* xr = (const float4*)(X + (size_t)row * D);
  float4 a = xr[lane];
  float4 b = xr[lane + 64];
  float ss = a.x*a.x + a.y*a.y + a.z*a.z + a.w*a.w
           + b.x*b.x + b.y*b.y + b.z*b.z + b.w*b.w;
  #pragma unroll
  for (int off = 1; off < 64; off <<= 1) ss += __shfl_xor(ss, off, 64);
  float r = rsqrtf(ss);
  int lo = 0, hi = 0;
  lo = __builtin_amdgcn_cvt_pk_fp8_f32(a.x*r, a.y*r, lo, false);
  lo = __builtin_amdgcn_cvt_pk_fp8_f32(a.z*r, a.w*r, lo, true);
  hi = __builtin_amdgcn_cvt_pk_fp8_f32(b.x*r, b.y*r, hi, false);
  hi = __builtin_amdgcn_cvt_pk_fp8_f32(b.z*r, b.w*r, hi, true);
  unsigned char* op = Fq + (size_t)row * D;
  *(int*)(op + lane * 4)       = lo;
  *(int*)(op + 256 + lane * 4) = hi;
}

// Symmetric SupCon GEMM, chunk-pair enumeration (XCD-local, balanced).
// Upper-triangle 128x128 tiles (I <= J), grouped by aligned 4-col-tile
// chunks m (cols 4m..4m+3). Chunk m has rows I = 0..4m+3. Chunk pair
// {Q, 15-Q} = exactly 68 blocks / 520 half-steps -> blockIdx = k*8+Q gives
// XCD Q only cols of chunks {Q,15-Q} (512 KB, L2-resident) and equal work.
//   k<4Q+1      : full  (m=Q,    I=k)
//   k<62        : full  (m=15-Q, I=k-4Q-1)
//   k<65        : part  (m=Q,    I=4Q+1+(k-62))     (shortest blocks last
//   else        : part  (m=15-Q, I=4(15-Q)+1+(k-65)) -> they backfill)
// Block: A = rows of tile I (registers); walk j = jlo..4m+3 (jlo =
// max(4m,I), contiguous) as 2..8 pipelined 64-col half-steps (R2-proven
// counted vmcnt(8) + raw-barrier double-buffer). exp folded into row sums
// (se/ms) and per-col-tile sums (ce/cm). Diagonal tile (j==I, only in
// jlo==I blocks at c=0) computed in full, col-side skipped.
// Partials psum[slot][row]: row-side slot=m, col-side slot=16+I; every
// (slot,row) has exactly one writer; diagonal blocks zero-fill the
// never-written (slot,row) pairs (replaces the psum memset dispatch).
__global__ __launch_bounds__(256, 1)
void kmain(const unsigned char* __restrict__ F, const int* __restrict__ tgt,
           float* __restrict__ psum, float* __restrict__ pmask, int N, int D) {
  __shared__ __align__(16) unsigned char Bs[2][64 * 512];  // 2 x 32 KB dbuf
  __shared__ float cred[2][4][128];
  __shared__ int tgts[512];

  const int tid  = threadIdx.x;
  const int lane = tid & 63;
  const int wave = tid >> 6;
  const int quad = lane >> 4;
  const int l15  = lane & 15;

  const int b  = blockIdx.x;
  const int Q  = b & 7;
  const int k  = b >> 3;
  const int M1 = 15 - Q;
  int mc, I;
  if (k < 4*Q + 1) { mc = Q;  I = k; }
  else if (k < 62) { mc = M1; I = k - 4*Q - 1; }
  else if (k < 65) { mc = Q;  I = 4*Q + 1 + (k - 62); }
  else             { mc = M1; I = 4*M1 + 1 + (k - 65); }
  const int jlo     = (4*mc > I) ? 4*mc : I;
  const int ntiles  = 4*mc + 4 - jlo;       // 1..4
  const int lim     = 2 * ntiles;
  const int rowbase = I * 128;
  const bool diagblk = (jlo == I);          // contains diag tile at c=0

  // ---- zero-fill duty (diagonal blocks only): row-slots m' < mc and
  // col-slots s >= I at this tile's 128 rows have no other writer.
  if (diagblk) {
    float* P = (tid >> 7) ? pmask : psum;
    const int r = tid & 127;
    for (int mp = 0; mp < mc; ++mp)
      P[(size_t)mp * N + rowbase + r] = 0.f;
    for (int s = I; s < 64; ++s)
      P[(size_t)(NROWSLOT + s) * N + rowbase + r] = 0.f;
  }

  // ---- A fragments: 2 mi x 4 ksteps x 32 fp8 ----
  i32x8 af[2][4];
  #pragma unroll
  for (int mi = 0; mi < 2; ++mi) {
    const unsigned char* rp = F + (size_t)(rowbase + wave*32 + mi*16 + l15) * 512 + quad*32;
    #pragma unroll
    for (int ks = 0; ks < 4; ++ks) {
      i32x4 lo = *(const i32x4*)(rp + ks*128);
      i32x4 hi = *(const i32x4*)(rp + ks*128 + 16);
      af[mi][ks] = __builtin_shufflevector(lo, hi, 0,1,2,3,4,5,6,7);
    }
  }

  int trow[2][4];
  #pragma unroll
  for (int mi = 0; mi < 2; ++mi)
    #pragma unroll
    for (int r = 0; r < 4; ++r)
      trow[mi][r] = tgt[rowbase + wave*32 + mi*16 + quad*4 + r];

  // col targets for the block's tiles (contiguous) -> LDS
  for (int i = tid; i < ntiles * 128; i += 256)
    tgts[i] = tgt[jlo * 128 + i];

  float se[2][4], ms[2][4];
  #pragma unroll
  for (int mi = 0; mi < 2; ++mi)
    #pragma unroll
    for (int r = 0; r < 4; ++r) { se[mi][r] = 0.f; ms[mi][r] = 0.f; }
  f32x4 ce[4][2], cm[4][2];
  #pragma unroll
  for (int c = 0; c < 4; ++c)
    #pragma unroll
    for (int h = 0; h < 2; ++h) {
      ce[c][h] = (f32x4){0,0,0,0};
      cm[c][h] = (f32x4){0,0,0,0};
    }

  const float C1 = (1.0f / TEMP) * 1.4426950408889634f;
  const float C0 = -C1;
  const int sw0 = (quad * 2) ^ (l15 & 7);

  // stage half-step s (tile jlo+(s>>1), half s&1): 64 rows x 512 B.
  // phys 16B-slot p in a row holds logical slot p^(row&7).
  auto STAGE = [&](int s) {
    const int rbase = (jlo + (s >> 1)) * 128 + (s & 1) * 64;
    unsigned char* db = &Bs[0][0] + (s & 1) * 32768;
    #pragma unroll
    for (int it = 0; it < 8; ++it) {
      const int L   = it * 256 + tid;
      const int row = L >> 5;
      const int ks  = (L & 31) ^ (row & 7);
      const unsigned char* gp = F + (size_t)(rbase + row) * 512 + ks * 16;
      __builtin_amdgcn_global_load_lds(
          (const __attribute__((address_space(1))) void*)gp,
          (__attribute__((address_space(3))) void*)(db + L * 16), 16, 0, 0);
    }
  };

  auto COMP = [&](int p) {
    const int c = p >> 1, h = p & 1;
    f32x4 acc[2][4];
    #pragma unroll
    for (int mi = 0; mi < 2; ++mi)
      #pragma unroll
      for (int ni = 0; ni < 4; ++ni)
        acc[mi][ni] = (f32x4){0.f, 0.f, 0.f, 0.f};

    const unsigned char* bb  = &Bs[0][0] + (p & 1) * 32768 + l15 * 512;
    const unsigned char* bp0 = bb + sw0 * 16;
    const unsigned char* bp1 = bb + (sw0 ^ 1) * 16;

    #pragma unroll
    for (int ks = 0; ks < 4; ++ks) {
      #pragma unroll
      for (int ni = 0; ni < 4; ++ni) {
        i32x4 b0 = *(const i32x4*)(bp0 + ni*8192 + ks*128);
        i32x4 b1 = *(const i32x4*)(bp1 + ni*8192 + ks*128);
        i32x8 bv = __builtin_shufflevector(b0, b1, 0,1,2,3,4,5,6,7);
        acc[0][ni] = __builtin_amdgcn_mfma_scale_f32_16x16x128_f8f6f4(
            af[0][ks], bv, acc[0][ni], 0, 0, 0, 0x7F7F7F7F, 0, 0x7F7F7F7F);
        acc[1][ni] = __builtin_amdgcn_mfma_scale_f32_16x16x128_f8f6f4(
            af[1][ks], bv, acc[1][ni], 0, 0, 0, 0x7F7F7F7F, 0, 0x7F7F7F7F);
      }
    }

    int tcg[4];
    #pragma unroll
    for (int ni = 0; ni < 4; ++ni) tcg[ni] = tgts[c*128 + h*64 + ni*16 + l15];
    #pragma unroll
    for (int mi = 0; mi < 2; ++mi)
      #pragma unroll
      for (int ni = 0; ni < 4; ++ni)
        #pragma unroll
        for (int r = 0; r < 4; ++r) {
          float v = acc[mi][ni][r];
          float e = __builtin_amdgcn_exp2f(fmaf(v, C1, C0));
          se[mi][r]    += e;
          ce[c][h][ni] += e;
          if (tcg[ni] == trow[mi][r]) { ms[mi][r] += v; cm[c][h][ni] += v; }
        }
  };

  __syncthreads();            // tgts visible; prologue retires
  STAGE(0);                   // 8 loads in flight

  #pragma unroll
  for (int p = 0; p < 8; ++p) {
    if (p < lim) {            // block-uniform
      if (p + 1 < lim) {
        STAGE(p + 1);         // 16 in flight
        asm volatile("s_waitcnt vmcnt(8)" ::: "memory");  // step p landed
      } else {
        asm volatile("s_waitcnt vmcnt(0)" ::: "memory");
      }
      __builtin_amdgcn_s_barrier();
      COMP(p);
      __builtin_amdgcn_s_barrier();   // buf reads done before next overwrite
    }
  }

  // ---- row-side partials -> slot mc ----
  #pragma unroll
  for (int mi = 0; mi < 2; ++mi)
    #pragma unroll
    for (int r = 0; r < 4; ++r) {
      float s = se[mi][r], mm = ms[mi][r];
      #pragma unroll
      for (int off = 1; off < 16; off <<= 1) {
        s  += __shfl_xor(s, off, 64);
        mm += __shfl_xor(mm, off, 64);
      }
      if (l15 == 0) {
        int row = rowbase + wave*32 + mi*16 + quad*4 + r;
        psum [(size_t)mc * N + row] = s;
        pmask[(size_t)mc * N + row] = mm;
      }
    }

  // ---- col-side partials: tile c -> slot 16+I, rows (jlo+c)*128.. ----
  #pragma unroll
  for (int c = 0; c < 4; ++c) {
    const bool havec = (c < ntiles) && !(diagblk && c == 0);  // block-uniform
    if (havec) {
      #pragma unroll
      for (int g = 0; g < 2; ++g)
        #pragma unroll
        for (int ni = 0; ni < 4; ++ni) {
          float e  = ce[c][g][ni];
          float mm = cm[c][g][ni];
          e  += __shfl_xor(e, 16, 64);  e  += __shfl_xor(e, 32, 64);
          mm += __shfl_xor(mm, 16, 64); mm += __shfl_xor(mm, 32, 64);
          if (quad == 0) {
            cred[0][wave][g*64 + ni*16 + l15] = e;
            cred[1][wave][g*64 + ni*16 + l15] = mm;
          }
        }
    }
    __syncthreads();
    if (havec && tid < 128) {
      float s  = cred[0][0][tid] + cred[0][1][tid] + cred[0][2][tid] + cred[0][3][tid];
      float mm = cred[1][0][tid] + cred[1][1][tid] + cred[1][2][tid] + cred[1][3][tid];
      psum [(size_t)(NROWSLOT + I) * N + (jlo + c) * 128 + tid] = s;
      pmask[(size_t)(NROWSLOT + I) * N + (jlo + c) * 128 + tid] = mm;
    }
    __syncthreads();
  }
}

// finalize: 32 blocks x 256 rows; per-block histogram, per-row term,
// wave reduce, one atomicAdd per block into pre-zeroed out.
__global__ __launch_bounds__(256) void kfinal(
    const float* __restrict__ psum, const float* __restrict__ pmask,
    const int* __restrict__ tgt, float* __restrict__ out, int N, int nslot) {
  __shared__ int h[128];
  __shared__ float wsum[4];
  const int tid = threadIdx.x;
  if (tid < 128) h[tid] = 0;
  __syncthreads();
  for (int i = tid; i < N; i += 256) atomicAdd(&h[tgt[i] & 127], 1);
  __syncthreads();

  const int i = blockIdx.x * 256 + tid;
  float s = 0.f, m = 0.f;
  #pragma unroll 8
  for (int sp = 0; sp < nslot; ++sp) {
    s += psum[(size_t)sp * N + i];
    m += pmask[(size_t)sp * N + i];
  }
  const float invT = 1.0f / TEMP;
  float cnt = (float)(h[tgt[i] & 127] - 1);
  float term = (m - 1.0f) * invT / cnt - (logf(s) + invT);
  #pragma unroll
  for (int off = 1; off < 64; off <<= 1) term += __shfl_xor(term, off, 64);
  if ((tid & 63) == 0) wsum[tid >> 6] = term;
  __syncthreads();
  if (tid == 0)
    atomicAdd(out, -(wsum[0] + wsum[1] + wsum[2] + wsum[3]) / (float)N);
}

extern "C" void kernel_launch(void* const* d_in, const int* in_sizes, int n_in,
                              void* d_out, int out_size, void* d_ws, size_t ws_size,
                              hipStream_t stream) {
  const float* X  = (const float*)d_in[0];
  const int* tgt  = (const int*)d_in[1];
  float* out      = (float*)d_out;
  const int N = in_sizes[1];
  const int D = in_sizes[0] / N;

  char* w = (char*)d_ws;
  unsigned char* Fq = (unsigned char*)w;
  size_t off = (size_t)N * D;                           // fp8: 1 B/elem (4 MB)
  float* psum  = (float*)(w + off);
  size_t psz = (size_t)NSLOT * N * sizeof(float);       // 2.62 MB
  off += psz;
  float* pmask = (float*)(w + off);                     // total ws ~9.5 MB

  // 3 dispatches (was 5): out zeroed by knorm; psum gaps zero-filled in kmain.
  knorm<<<N / 4, 256, 0, stream>>>(X, Fq, out, D);
  kmain<<<544, 256, 0, stream>>>(Fq, tgt, psum, pmask, N, D);
  kfinal<<<N / 256, 256, 0, stream>>>(psum, pmask, tgt, out, N, NSLOT);
}